// Round 1
// baseline (3362.205 us; speedup 1.0000x reference)
//
#include <hip/hip_runtime.h>
#include <math.h>

#define N_NODES 50000
#define N_EDGES 800000
#define N_EP    850000   // E + N self loops
#define E_DIM   5
#define N_G     128
#define N_ACT   8

__device__ __forceinline__ void atomicMaxF(float* addr, float val) {
    // works for all finite floats when slot initialized to -inf (0xFF800000)
    if (val >= 0.f) atomicMax((int*)addr, __float_as_int(val));
    else            atomicMin((unsigned int*)addr, (unsigned int)__float_as_int(val));
}

// weff[l][d][h] = sum_c We_l[d, h*32+c] * ae_l[h, c]   (10 floats per layer)
__global__ void weff_kernel(const float* __restrict__ We1, const float* __restrict__ ae1,
                            const float* __restrict__ We2, const float* __restrict__ ae2,
                            const float* __restrict__ We3, const float* __restrict__ ae3,
                            float* __restrict__ weff) {
    int t = threadIdx.x;
    if (t >= 30) return;
    int l = t / 10, r = t % 10, d = r >> 1, h = r & 1;
    const float* We = (l == 0) ? We1 : (l == 1) ? We2 : We3;
    const float* ae = (l == 0) ? ae1 : (l == 1) ? ae2 : ae3;
    float s = 0.f;
    for (int c = 0; c < 32; ++c) s += We[d * 64 + h * 32 + c] * ae[h * 32 + c];
    weff[l * 10 + d * 2 + h] = s;
}

// deg[dst] += 1 ; loop_sum[dst] += edge_attr  (original E edges only)
__global__ void loop_attr_kernel(const int* __restrict__ ei, const float* __restrict__ ea,
                                 float* __restrict__ loop_sum, float* __restrict__ deg) {
    int k = blockIdx.x * blockDim.x + threadIdx.x;
    if (k >= N_EDGES) return;
    int d = ei[N_EDGES + k];
    atomicAdd(&deg[d], 1.f);
    const float* ep = ea + (size_t)k * E_DIM;
    float* lp = loop_sum + (size_t)d * E_DIM;
    #pragma unroll
    for (int j = 0; j < E_DIM; ++j) atomicAdd(lp + j, ep[j]);
}

__global__ void fill_neginf_kernel(float* p, int n) {
    int i = blockIdx.x * blockDim.x + threadIdx.x;
    if (i < n) ((int*)p)[i] = 0xFF800000;  // -inf
}

// xs = in @ W   ; a_srcv[n,h] = xs[n,h,:]·a_s[h,:] ; a_dstv likewise
template <int DIN>
__global__ __launch_bounds__(256) void feat_kernel(
    const float* __restrict__ in, const float* __restrict__ W,
    const float* __restrict__ a_s, const float* __restrict__ a_d,
    float* __restrict__ xs, float* __restrict__ a_srcv, float* __restrict__ a_dstv) {
    __shared__ float Wl[DIN * 64];
    __shared__ float asl[64], adl[64];
    int tid = threadIdx.x;
    for (int i = tid; i < DIN * 64; i += 256) Wl[i] = W[i];
    if (tid < 64) { asl[tid] = a_s[tid]; adl[tid] = a_d[tid]; }
    __syncthreads();
    int n = blockIdx.x * 256 + tid;
    if (n >= N_NODES) return;
    float acc[64];
    #pragma unroll
    for (int j = 0; j < 64; ++j) acc[j] = 0.f;
    const float* row = in + (size_t)n * DIN;
    for (int k = 0; k < DIN; ++k) {
        float xk = row[k];
        #pragma unroll
        for (int j = 0; j < 64; ++j) acc[j] += xk * Wl[k * 64 + j];
    }
    float s0 = 0, s1 = 0, d0 = 0, d1 = 0;
    #pragma unroll
    for (int c = 0; c < 32; ++c) {
        s0 += acc[c] * asl[c];           d0 += acc[c] * adl[c];
        s1 += acc[32 + c] * asl[32 + c]; d1 += acc[32 + c] * adl[32 + c];
    }
    a_srcv[n * 2 + 0] = s0; a_srcv[n * 2 + 1] = s1;
    a_dstv[n * 2 + 0] = d0; a_dstv[n * 2 + 1] = d1;
    float4* o = (float4*)(xs + (size_t)n * 64);
    #pragma unroll
    for (int j = 0; j < 16; ++j)
        o[j] = make_float4(acc[4 * j], acc[4 * j + 1], acc[4 * j + 2], acc[4 * j + 3]);
}

// pass A: logits + segment max over dst
__global__ void edge_logits_kernel(
    const int* __restrict__ ei, const float* __restrict__ ea,
    const float* __restrict__ loop_sum, const float* __restrict__ deg,
    const float* __restrict__ weff,  // 10 floats for this layer, [d*2+h]
    const float* __restrict__ a_srcv, const float* __restrict__ a_dstv,
    float* __restrict__ logits, float* __restrict__ m) {
    int k = blockIdx.x * blockDim.x + threadIdx.x;
    if (k >= N_EP) return;
    int s, d;
    float e[5];
    if (k < N_EDGES) {
        s = ei[k]; d = ei[N_EDGES + k];
        const float* ep = ea + (size_t)k * E_DIM;
        #pragma unroll
        for (int j = 0; j < 5; ++j) e[j] = ep[j];
    } else {
        int i = k - N_EDGES; s = i; d = i;
        float inv = 1.f / fmaxf(deg[i], 1.f);
        const float* lp = loop_sum + (size_t)i * E_DIM;
        #pragma unroll
        for (int j = 0; j < 5; ++j) e[j] = lp[j] * inv;
    }
    float ae0 = 0.f, ae1 = 0.f;
    #pragma unroll
    for (int j = 0; j < 5; ++j) { ae0 += e[j] * weff[j * 2]; ae1 += e[j] * weff[j * 2 + 1]; }
    float l0 = a_srcv[s * 2]     + a_dstv[d * 2]     + ae0;
    float l1 = a_srcv[s * 2 + 1] + a_dstv[d * 2 + 1] + ae1;
    l0 = (l0 > 0.f) ? l0 : 0.2f * l0;   // leaky_relu slope 0.2
    l1 = (l1 > 0.f) ? l1 : 0.2f * l1;
    logits[(size_t)k * 2]     = l0;
    logits[(size_t)k * 2 + 1] = l1;
    atomicMaxF(&m[d * 2], l0);
    atomicMaxF(&m[d * 2 + 1], l1);
}

// pass B: ex = exp(logit - m[dst]) ; den[dst] += ex   (logits buffer overwritten with ex)
__global__ void edge_exp_kernel(const int* __restrict__ ei, const float* __restrict__ m,
                                float* __restrict__ logits, float* __restrict__ den) {
    int k = blockIdx.x * blockDim.x + threadIdx.x;
    if (k >= N_EP) return;
    int d = (k < N_EDGES) ? ei[N_EDGES + k] : (k - N_EDGES);
    float ex0 = expf(logits[(size_t)k * 2]     - m[d * 2]);
    float ex1 = expf(logits[(size_t)k * 2 + 1] - m[d * 2 + 1]);
    logits[(size_t)k * 2]     = ex0;
    logits[(size_t)k * 2 + 1] = ex1;
    atomicAdd(&den[d * 2], ex0);
    atomicAdd(&den[d * 2 + 1], ex1);
}

// pass C: agg[dst] += alpha * xs[src]   (16 threads per edge, 4 floats each)
__global__ void edge_msg_kernel(const int* __restrict__ ei, const float* __restrict__ exv,
                                const float* __restrict__ den, const float* __restrict__ xs,
                                float* __restrict__ agg) {
    long long gid = (long long)blockIdx.x * blockDim.x + threadIdx.x;
    int k = (int)(gid >> 4);
    int t = (int)(gid & 15);
    if (k >= N_EP) return;
    int s, d;
    if (k < N_EDGES) { s = ei[k]; d = ei[N_EDGES + k]; } else { s = k - N_EDGES; d = s; }
    int h = t >> 3;
    float alpha = exv[(size_t)k * 2 + h] / (den[d * 2 + h] + 1e-16f);
    float4 xv = *(const float4*)(xs + (size_t)s * 64 + t * 4);
    float* ap = agg + (size_t)d * 64 + t * 4;
    atomicAdd(ap + 0, xv.x * alpha);
    atomicAdd(ap + 1, xv.y * alpha);
    atomicAdd(ap + 2, xv.z * alpha);
    atomicAdd(ap + 3, xv.w * alpha);
}

__global__ void finalize_kernel(const float* __restrict__ agg, const float* __restrict__ b,
                                float* __restrict__ out, int relu) {
    int i = blockIdx.x * blockDim.x + threadIdx.x;
    if (i >= N_NODES * 64) return;
    float v = agg[i] + b[i & 63];
    if (relu) v = fmaxf(v, 0.f);
    out[i] = v;
}

__global__ void pool_kernel(const float* __restrict__ h, const int* __restrict__ batch,
                            float* __restrict__ pooled, float* __restrict__ cnt) {
    int i = blockIdx.x * blockDim.x + threadIdx.x;
    if (i >= N_NODES * 64) return;
    int n = i >> 6, j = i & 63;
    int g = batch[n];
    atomicAdd(&pooled[g * 64 + j], h[i]);
    if (j == 0) atomicAdd(&cnt[g], 1.f);
}

__global__ void head_kernel(const float* __restrict__ pooled, const float* __restrict__ cnt,
                            const float* __restrict__ Wl, const float* __restrict__ bl,
                            float* __restrict__ out) {
    int t = blockIdx.x * blockDim.x + threadIdx.x;
    if (t >= N_G * N_ACT) return;
    int g = t >> 3, a = t & 7;
    float inv = 1.f / fmaxf(cnt[g], 1.f);
    float s = bl[a];
    #pragma unroll
    for (int j = 0; j < 64; ++j) s += pooled[g * 64 + j] * inv * Wl[j * 8 + a];
    out[t] = tanhf(s);
}

extern "C" void kernel_launch(void* const* d_in, const int* in_sizes, int n_in,
                              void* d_out, int out_size, void* d_ws, size_t ws_size,
                              hipStream_t stream) {
    const float* x    = (const float*)d_in[0];
    const int*   ei   = (const int*)d_in[1];
    const float* ea   = (const float*)d_in[2];
    const int*   batch= (const int*)d_in[3];
    const float* W[3]   = {(const float*)d_in[4],  (const float*)d_in[10], (const float*)d_in[16]};
    const float* We[3]  = {(const float*)d_in[5],  (const float*)d_in[11], (const float*)d_in[17]};
    const float* as_[3] = {(const float*)d_in[6],  (const float*)d_in[12], (const float*)d_in[18]};
    const float* ad_[3] = {(const float*)d_in[7],  (const float*)d_in[13], (const float*)d_in[19]};
    const float* ae_[3] = {(const float*)d_in[8],  (const float*)d_in[14], (const float*)d_in[20]};
    const float* b_[3]  = {(const float*)d_in[9],  (const float*)d_in[15], (const float*)d_in[21]};
    const float* Wlin = (const float*)d_in[22];
    const float* bl   = (const float*)d_in[23];
    float* out = (float*)d_out;

    float* ws = (float*)d_ws;
    size_t off = 0;
    float* A      = ws + off; off += (size_t)N_NODES * 64;   // layer io
    float* B      = ws + off; off += (size_t)N_NODES * 64;   // xs
    float* agg    = ws + off; off += (size_t)N_NODES * 64;
    float* logits = ws + off; off += (size_t)N_EP * 2;
    float* a_srcv = ws + off; off += N_NODES * 2;
    float* a_dstv = ws + off; off += N_NODES * 2;
    float* mbuf   = ws + off; off += N_NODES * 2;
    float* den    = ws + off; off += N_NODES * 2;
    float* lsum   = ws + off; off += (size_t)N_NODES * 5;
    float* deg    = ws + off; off += N_NODES;
    float* weff   = ws + off; off += 32;
    float* pooled = ws + off; off += N_G * 64;
    float* cnt    = ws + off; off += N_G;

    // once per call
    hipMemsetAsync(lsum, 0, (size_t)N_NODES * 5 * sizeof(float), stream);
    hipMemsetAsync(deg, 0, N_NODES * sizeof(float), stream);
    hipMemsetAsync(pooled, 0, (N_G * 64 + N_G) * sizeof(float), stream);  // pooled+cnt contiguous
    weff_kernel<<<1, 32, 0, stream>>>(We[0], ae_[0], We[1], ae_[1], We[2], ae_[2], weff);
    loop_attr_kernel<<<(N_EDGES + 255) / 256, 256, 0, stream>>>(ei, ea, lsum, deg);

    const int EB = (N_EP + 255) / 256;
    for (int l = 0; l < 3; ++l) {
        if (l == 0)
            feat_kernel<32><<<(N_NODES + 255) / 256, 256, 0, stream>>>(x, W[0], as_[0], ad_[0], B, a_srcv, a_dstv);
        else
            feat_kernel<64><<<(N_NODES + 255) / 256, 256, 0, stream>>>(A, W[l], as_[l], ad_[l], B, a_srcv, a_dstv);
        hipMemsetAsync(agg, 0, (size_t)N_NODES * 64 * sizeof(float), stream);
        hipMemsetAsync(den, 0, N_NODES * 2 * sizeof(float), stream);
        fill_neginf_kernel<<<(N_NODES * 2 + 255) / 256, 256, 0, stream>>>(mbuf, N_NODES * 2);
        edge_logits_kernel<<<EB, 256, 0, stream>>>(ei, ea, lsum, deg, weff + l * 10,
                                                   a_srcv, a_dstv, logits, mbuf);
        edge_exp_kernel<<<EB, 256, 0, stream>>>(ei, mbuf, logits, den);
        edge_msg_kernel<<<(int)(((size_t)N_EP * 16 + 255) / 256), 256, 0, stream>>>(ei, logits, den, B, agg);
        finalize_kernel<<<(N_NODES * 64 + 255) / 256, 256, 0, stream>>>(agg, b_[l], A, l < 2 ? 1 : 0);
    }
    pool_kernel<<<(N_NODES * 64 + 255) / 256, 256, 0, stream>>>(A, batch, pooled, cnt);
    head_kernel<<<(N_G * N_ACT + 255) / 256, 256, 0, stream>>>(pooled, cnt, Wlin, bl, out);
}

// Round 2
// 1145.855 us; speedup vs baseline: 2.9342x; 2.9342x over previous
//
#include <hip/hip_runtime.h>
#include <math.h>

#define N_NODES 50000
#define N_EDGES 800000
#define N_EP    850000   // E + N self loops
#define E_DIM   5
#define N_G     128
#define N_ACT   8

// ---------------- once-per-call setup kernels ----------------

// weff[l][d][h] = sum_c We_l[d, h*32+c] * ae_l[h, c]   (10 floats per layer)
__global__ void weff_kernel(const float* __restrict__ We1, const float* __restrict__ ae1,
                            const float* __restrict__ We2, const float* __restrict__ ae2,
                            const float* __restrict__ We3, const float* __restrict__ ae3,
                            float* __restrict__ weff) {
    int t = threadIdx.x;
    if (t >= 30) return;
    int l = t / 10, r = t % 10, d = r >> 1, h = r & 1;
    const float* We = (l == 0) ? We1 : (l == 1) ? We2 : We3;
    const float* ae = (l == 0) ? ae1 : (l == 1) ? ae2 : ae3;
    float s = 0.f;
    for (int c = 0; c < 32; ++c) s += We[d * 64 + h * 32 + c] * ae[h * 32 + c];
    weff[l * 10 + d * 2 + h] = s;
}

// deg[dst] += 1 ; loop_sum[dst] += edge_attr ; hist[dst]++   (original E edges)
__global__ void loop_attr_kernel(const int* __restrict__ ei, const float* __restrict__ ea,
                                 float* __restrict__ loop_sum, float* __restrict__ deg,
                                 int* __restrict__ hist) {
    int k = blockIdx.x * blockDim.x + threadIdx.x;
    if (k >= N_EDGES) return;
    int d = ei[N_EDGES + k];
    atomicAdd(&deg[d], 1.f);
    atomicAdd(&hist[d], 1);
    const float* ep = ea + (size_t)k * E_DIM;
    float* lp = loop_sum + (size_t)d * E_DIM;
    #pragma unroll
    for (int j = 0; j < E_DIM; ++j) atomicAdd(lp + j, ep[j]);
}

// exclusive scan of (hist[i]+1) over 50000 nodes, single block of 1024
__global__ __launch_bounds__(1024) void scan_kernel(const int* __restrict__ hist,
                                                    int* __restrict__ rowptr) {
    __shared__ int sm[1024];
    const int C = (N_NODES + 1023) / 1024;  // 49
    int t = threadIdx.x;
    int beg = t * C, end = min(beg + C, N_NODES);
    int s = 0;
    for (int i = beg; i < end; ++i) s += hist[i] + 1;
    sm[t] = s;
    __syncthreads();
    for (int off = 1; off < 1024; off <<= 1) {
        int v = (t >= off) ? sm[t - off] : 0;
        __syncthreads();
        sm[t] += v;
        __syncthreads();
    }
    int excl = (t == 0) ? 0 : sm[t - 1];
    for (int i = beg; i < end; ++i) { rowptr[i] = excl; excl += hist[i] + 1; }
    if (t == 1023) rowptr[N_NODES] = excl;  // == N_EP
}

// scatter edges (incl. self loops) into dst-sorted order
__global__ void scatter_kernel(const int* __restrict__ ei, const float* __restrict__ ea,
                               const float* __restrict__ lsum, const float* __restrict__ deg,
                               const int* __restrict__ rowptr, int* __restrict__ cur,
                               int* __restrict__ srcS, int* __restrict__ dstS,
                               float* __restrict__ eaS) {
    int k = blockIdx.x * blockDim.x + threadIdx.x;
    if (k >= N_EP) return;
    int s, d;
    float e[5];
    if (k < N_EDGES) {
        s = ei[k]; d = ei[N_EDGES + k];
        const float* ep = ea + (size_t)k * E_DIM;
        #pragma unroll
        for (int j = 0; j < 5; ++j) e[j] = ep[j];
    } else {
        int i = k - N_EDGES; s = i; d = i;
        float inv = 1.f / fmaxf(deg[i], 1.f);
        const float* lp = lsum + (size_t)i * E_DIM;
        #pragma unroll
        for (int j = 0; j < 5; ++j) e[j] = lp[j] * inv;
    }
    int pos = rowptr[d] + atomicAdd(&cur[d], 1);
    srcS[pos] = s;
    dstS[pos] = d;
    float* op = eaS + (size_t)pos * E_DIM;
    #pragma unroll
    for (int j = 0; j < 5; ++j) op[j] = e[j];
}

// ---------------- per-layer kernels ----------------

// xs = in @ W ; a_srcv[n,h] = xs[n,h,:]·a_s[h,:] ; a_dstv likewise
template <int DIN>
__global__ __launch_bounds__(256) void feat_kernel(
    const float* __restrict__ in, const float* __restrict__ W,
    const float* __restrict__ a_s, const float* __restrict__ a_d,
    float* __restrict__ xs, float* __restrict__ a_srcv, float* __restrict__ a_dstv) {
    __shared__ float Wl[DIN * 64];
    __shared__ float asl[64], adl[64];
    int tid = threadIdx.x;
    for (int i = tid; i < DIN * 64; i += 256) Wl[i] = W[i];
    if (tid < 64) { asl[tid] = a_s[tid]; adl[tid] = a_d[tid]; }
    __syncthreads();
    int n = blockIdx.x * 256 + tid;
    if (n >= N_NODES) return;
    float acc[64];
    #pragma unroll
    for (int j = 0; j < 64; ++j) acc[j] = 0.f;
    const float* row = in + (size_t)n * DIN;
    for (int k = 0; k < DIN; ++k) {
        float xk = row[k];
        #pragma unroll
        for (int j = 0; j < 64; ++j) acc[j] += xk * Wl[k * 64 + j];
    }
    float s0 = 0, s1 = 0, d0 = 0, d1 = 0;
    #pragma unroll
    for (int c = 0; c < 32; ++c) {
        s0 += acc[c] * asl[c];           d0 += acc[c] * adl[c];
        s1 += acc[32 + c] * asl[32 + c]; d1 += acc[32 + c] * adl[32 + c];
    }
    a_srcv[n * 2 + 0] = s0; a_srcv[n * 2 + 1] = s1;
    a_dstv[n * 2 + 0] = d0; a_dstv[n * 2 + 1] = d1;
    float4* o = (float4*)(xs + (size_t)n * 64);
    #pragma unroll
    for (int j = 0; j < 16; ++j)
        o[j] = make_float4(acc[4 * j], acc[4 * j + 1], acc[4 * j + 2], acc[4 * j + 3]);
}

// logits in sorted-edge order (no atomics)
__global__ void logits_kernel(const int* __restrict__ srcS, const int* __restrict__ dstS,
                              const float* __restrict__ eaS, const float* __restrict__ weff,
                              const float* __restrict__ a_srcv, const float* __restrict__ a_dstv,
                              float* __restrict__ logitsS) {
    int j = blockIdx.x * blockDim.x + threadIdx.x;
    if (j >= N_EP) return;
    int s = srcS[j], d = dstS[j];
    const float* ep = eaS + (size_t)j * E_DIM;
    float ae0 = 0.f, ae1 = 0.f;
    #pragma unroll
    for (int i = 0; i < 5; ++i) { ae0 += ep[i] * weff[i * 2]; ae1 += ep[i] * weff[i * 2 + 1]; }
    float l0 = a_srcv[s * 2]     + a_dstv[d * 2]     + ae0;
    float l1 = a_srcv[s * 2 + 1] + a_dstv[d * 2 + 1] + ae1;
    l0 = (l0 > 0.f) ? l0 : 0.2f * l0;
    l1 = (l1 > 0.f) ? l1 : 0.2f * l1;
    logitsS[(size_t)j * 2]     = l0;
    logitsS[(size_t)j * 2 + 1] = l1;
}

// one wave per node: softmax-max (coalesced+shfl), then serial edge loop
// accumulating Sum(ex * xs[src][lane]); alpha division factored out as 1/den.
__global__ __launch_bounds__(256) void node_agg_kernel(
    const int* __restrict__ rowptr, const int* __restrict__ srcS,
    const float* __restrict__ logitsS, const float* __restrict__ xs,
    const float* __restrict__ b, float* __restrict__ out, int relu) {
    int wid = blockIdx.x * 4 + (threadIdx.x >> 6);
    int lane = threadIdx.x & 63;
    if (wid >= N_NODES) return;
    int beg = rowptr[wid], end = rowptr[wid + 1];
    float m0 = -INFINITY, m1 = -INFINITY;
    for (int j = beg + lane; j < end; j += 64) {
        float2 l = *(const float2*)(logitsS + (size_t)j * 2);
        m0 = fmaxf(m0, l.x);
        m1 = fmaxf(m1, l.y);
    }
    #pragma unroll
    for (int off = 32; off; off >>= 1) {
        m0 = fmaxf(m0, __shfl_xor(m0, off));
        m1 = fmaxf(m1, __shfl_xor(m1, off));
    }
    int h = lane >> 5;
    float mh = h ? m1 : m0;
    float acc = 0.f, den0 = 0.f, den1 = 0.f;
    for (int j = beg; j < end; ++j) {
        float2 l = *(const float2*)(logitsS + (size_t)j * 2);
        float ex0 = expf(l.x - m0);
        float ex1 = expf(l.y - m1);
        den0 += ex0; den1 += ex1;
        int s = srcS[j];
        float exh = h ? ex1 : ex0;
        acc += exh * xs[(size_t)s * 64 + lane];
    }
    float den = (h ? den1 : den0) + 1e-16f;
    float v = acc / den + b[lane];
    if (relu) v = fmaxf(v, 0.f);
    out[(size_t)wid * 64 + lane] = v;
    (void)mh;
}

// ---------------- tail ----------------

__global__ void pool_kernel(const float* __restrict__ h, const int* __restrict__ batch,
                            float* __restrict__ pooled, float* __restrict__ cnt) {
    int i = blockIdx.x * blockDim.x + threadIdx.x;
    if (i >= N_NODES * 64) return;
    int n = i >> 6, j = i & 63;
    int g = batch[n];
    atomicAdd(&pooled[g * 64 + j], h[i]);
    if (j == 0) atomicAdd(&cnt[g], 1.f);
}

__global__ void head_kernel(const float* __restrict__ pooled, const float* __restrict__ cnt,
                            const float* __restrict__ Wl, const float* __restrict__ bl,
                            float* __restrict__ out) {
    int t = blockIdx.x * blockDim.x + threadIdx.x;
    if (t >= N_G * N_ACT) return;
    int g = t >> 3, a = t & 7;
    float inv = 1.f / fmaxf(cnt[g], 1.f);
    float s = bl[a];
    #pragma unroll
    for (int j = 0; j < 64; ++j) s += pooled[g * 64 + j] * inv * Wl[j * 8 + a];
    out[t] = tanhf(s);
}

extern "C" void kernel_launch(void* const* d_in, const int* in_sizes, int n_in,
                              void* d_out, int out_size, void* d_ws, size_t ws_size,
                              hipStream_t stream) {
    const float* x    = (const float*)d_in[0];
    const int*   ei   = (const int*)d_in[1];
    const float* ea   = (const float*)d_in[2];
    const int*   batch= (const int*)d_in[3];
    const float* W[3]   = {(const float*)d_in[4],  (const float*)d_in[10], (const float*)d_in[16]};
    const float* We[3]  = {(const float*)d_in[5],  (const float*)d_in[11], (const float*)d_in[17]};
    const float* as_[3] = {(const float*)d_in[6],  (const float*)d_in[12], (const float*)d_in[18]};
    const float* ad_[3] = {(const float*)d_in[7],  (const float*)d_in[13], (const float*)d_in[19]};
    const float* ae_[3] = {(const float*)d_in[8],  (const float*)d_in[14], (const float*)d_in[20]};
    const float* b_[3]  = {(const float*)d_in[9],  (const float*)d_in[15], (const float*)d_in[21]};
    const float* Wlin = (const float*)d_in[22];
    const float* bl   = (const float*)d_in[23];
    float* out = (float*)d_out;

    float* ws = (float*)d_ws;
    size_t off = 0;
    float* A      = ws + off; off += (size_t)N_NODES * 64;   // layer io
    float* B      = ws + off; off += (size_t)N_NODES * 64;   // xs
    float* logitsS= ws + off; off += (size_t)N_EP * 2;
    float* eaS    = ws + off; off += (size_t)N_EP * E_DIM;
    float* a_srcv = ws + off; off += N_NODES * 2;
    float* a_dstv = ws + off; off += N_NODES * 2;
    float* lsum   = ws + off; off += (size_t)N_NODES * E_DIM;
    float* deg    = ws + off; off += N_NODES;
    float* weff   = ws + off; off += 32;
    float* pooled = ws + off; off += N_G * 64;
    float* cnt    = ws + off; off += N_G;
    int* srcS   = (int*)(ws + off); off += N_EP;
    int* dstS   = (int*)(ws + off); off += N_EP;
    int* rowptr = (int*)(ws + off); off += N_NODES + 1;
    int* hist   = (int*)(ws + off); off += N_NODES;
    int* cur    = (int*)(ws + off); off += N_NODES;

    // ---- once-per-call setup ----
    hipMemsetAsync(lsum, 0, (size_t)N_NODES * E_DIM * sizeof(float), stream);
    hipMemsetAsync(deg, 0, N_NODES * sizeof(float), stream);
    hipMemsetAsync(hist, 0, N_NODES * sizeof(int), stream);
    hipMemsetAsync(cur, 0, N_NODES * sizeof(int), stream);
    hipMemsetAsync(pooled, 0, (N_G * 64 + N_G) * sizeof(float), stream);  // pooled+cnt contiguous
    weff_kernel<<<1, 32, 0, stream>>>(We[0], ae_[0], We[1], ae_[1], We[2], ae_[2], weff);
    loop_attr_kernel<<<(N_EDGES + 255) / 256, 256, 0, stream>>>(ei, ea, lsum, deg, hist);
    scan_kernel<<<1, 1024, 0, stream>>>(hist, rowptr);
    scatter_kernel<<<(N_EP + 255) / 256, 256, 0, stream>>>(ei, ea, lsum, deg, rowptr, cur,
                                                           srcS, dstS, eaS);

    const int EB = (N_EP + 255) / 256;
    for (int l = 0; l < 3; ++l) {
        if (l == 0)
            feat_kernel<32><<<(N_NODES + 255) / 256, 256, 0, stream>>>(x, W[0], as_[0], ad_[0], B, a_srcv, a_dstv);
        else
            feat_kernel<64><<<(N_NODES + 255) / 256, 256, 0, stream>>>(A, W[l], as_[l], ad_[l], B, a_srcv, a_dstv);
        logits_kernel<<<EB, 256, 0, stream>>>(srcS, dstS, eaS, weff + l * 10, a_srcv, a_dstv, logitsS);
        node_agg_kernel<<<(N_NODES + 3) / 4, 256, 0, stream>>>(rowptr, srcS, logitsS, B,
                                                               b_[l], A, l < 2 ? 1 : 0);
    }
    pool_kernel<<<(N_NODES * 64 + 255) / 256, 256, 0, stream>>>(A, batch, pooled, cnt);
    head_kernel<<<(N_G * N_ACT + 255) / 256, 256, 0, stream>>>(pooled, cnt, Wlin, bl, out);
}

// Round 3
// 624.544 us; speedup vs baseline: 5.3835x; 1.8347x over previous
//
#include <hip/hip_runtime.h>
#include <math.h>

#define N_NODES 50000
#define N_EDGES 800000
#define N_EP    850000   // E + N self loops
#define E_DIM   5
#define N_G     128
#define N_ACT   8

// ---------------- once-per-call setup kernels ----------------

// weff[l*10 + d*2 + h] = sum_c We_l[d, h*32+c] * ae_l[h, c]   (10 floats per layer)
__global__ void weff_kernel(const float* __restrict__ We1, const float* __restrict__ ae1,
                            const float* __restrict__ We2, const float* __restrict__ ae2,
                            const float* __restrict__ We3, const float* __restrict__ ae3,
                            float* __restrict__ weff) {
    int t = threadIdx.x;
    if (t >= 30) return;
    int l = t / 10, r = t % 10, d = r >> 1, h = r & 1;
    const float* We = (l == 0) ? We1 : (l == 1) ? We2 : We3;
    const float* ae = (l == 0) ? ae1 : (l == 1) ? ae2 : ae3;
    float s = 0.f;
    for (int c = 0; c < 32; ++c) s += We[d * 64 + h * 32 + c] * ae[h * 32 + c];
    weff[l * 10 + d * 2 + h] = s;
}

__global__ void hist_kernel(const int* __restrict__ ei, int* __restrict__ hist) {
    int k = blockIdx.x * blockDim.x + threadIdx.x;
    if (k < N_EDGES) atomicAdd(&hist[ei[N_EDGES + k]], 1);
}

// exclusive scan of (hist[i]+1) over N_NODES, single block of 1024
__global__ __launch_bounds__(1024) void scan_kernel(const int* __restrict__ hist,
                                                    int* __restrict__ rowptr) {
    __shared__ int sm[1024];
    const int C = (N_NODES + 1023) / 1024;
    int t = threadIdx.x;
    int beg = t * C, end = min(beg + C, N_NODES);
    int s = 0;
    for (int i = beg; i < end; ++i) s += hist[i] + 1;
    sm[t] = s;
    __syncthreads();
    for (int off = 1; off < 1024; off <<= 1) {
        int v = (t >= off) ? sm[t - off] : 0;
        __syncthreads();
        sm[t] += v;
        __syncthreads();
    }
    int excl = (t == 0) ? 0 : sm[t - 1];
    for (int i = beg; i < end; ++i) { rowptr[i] = excl; excl += hist[i] + 1; }
    if (t == 1023) rowptr[N_NODES] = excl;  // == N_EP
}

// scatter real edges dst-sorted; per-layer edge logit terms precomputed (ae = e . weff_l).
// Last slot of each row [rowptr[d+1]-1] is reserved for the self loop.
__global__ void scatter_kernel(const int* __restrict__ ei, const float* __restrict__ ea,
                               const float* __restrict__ weff,
                               const int* __restrict__ rowptr, int* __restrict__ cur,
                               int* __restrict__ srcS,
                               float* __restrict__ ae0, float* __restrict__ ae1,
                               float* __restrict__ ae2) {
    int k = blockIdx.x * blockDim.x + threadIdx.x;
    if (k >= N_EDGES) return;
    int s = ei[k], d = ei[N_EDGES + k];
    const float* ep = ea + (size_t)k * E_DIM;
    float e[5];
    #pragma unroll
    for (int j = 0; j < 5; ++j) e[j] = ep[j];
    int pos = rowptr[d] + atomicAdd(&cur[d], 1);
    srcS[pos] = s;
    float2 v0 = {0.f, 0.f}, v1 = {0.f, 0.f}, v2 = {0.f, 0.f};
    #pragma unroll
    for (int j = 0; j < 5; ++j) {
        v0.x += e[j] * weff[j * 2];      v0.y += e[j] * weff[j * 2 + 1];
        v1.x += e[j] * weff[10 + j * 2]; v1.y += e[j] * weff[10 + j * 2 + 1];
        v2.x += e[j] * weff[20 + j * 2]; v2.y += e[j] * weff[20 + j * 2 + 1];
    }
    ((float2*)ae0)[pos] = v0;
    ((float2*)ae1)[pos] = v1;
    ((float2*)ae2)[pos] = v2;
}

// fill self-loop slot of each row: srcS = node, ae = mean of row's real-edge ae (0 if none)
__global__ __launch_bounds__(256) void selfloop_kernel(
    const int* __restrict__ rowptr, int* __restrict__ srcS,
    float* __restrict__ ae0, float* __restrict__ ae1, float* __restrict__ ae2) {
    int wid = blockIdx.x * 4 + (threadIdx.x >> 6);
    int lane = threadIdx.x & 63;
    if (wid >= N_NODES) return;
    int beg = rowptr[wid], endAll = rowptr[wid + 1];
    int endReal = endAll - 1;
    float s0 = 0, s1 = 0, s2 = 0, s3 = 0, s4 = 0, s5 = 0;
    for (int j = beg + lane; j < endReal; j += 64) {
        float2 a = ((const float2*)ae0)[j]; s0 += a.x; s1 += a.y;
        float2 b = ((const float2*)ae1)[j]; s2 += b.x; s3 += b.y;
        float2 c = ((const float2*)ae2)[j]; s4 += c.x; s5 += c.y;
    }
    #pragma unroll
    for (int o = 32; o; o >>= 1) {
        s0 += __shfl_xor(s0, o); s1 += __shfl_xor(s1, o);
        s2 += __shfl_xor(s2, o); s3 += __shfl_xor(s3, o);
        s4 += __shfl_xor(s4, o); s5 += __shfl_xor(s5, o);
    }
    if (lane == 0) {
        float inv = 1.f / fmaxf((float)(endReal - beg), 1.f);
        srcS[endReal] = wid;
        ((float2*)ae0)[endReal] = make_float2(s0 * inv, s1 * inv);
        ((float2*)ae1)[endReal] = make_float2(s2 * inv, s3 * inv);
        ((float2*)ae2)[endReal] = make_float2(s4 * inv, s5 * inv);
    }
}

// group boundaries in sorted batch: gstart[g] = lower_bound(batch, g)
__global__ void gstart_kernel(const int* __restrict__ batch, int* __restrict__ gstart) {
    int g = threadIdx.x;
    if (g > N_G) return;
    int lo = 0, hi = N_NODES;
    while (lo < hi) { int mid = (lo + hi) >> 1; if (batch[mid] < g) lo = mid + 1; else hi = mid; }
    gstart[g] = lo;
}

// ---------------- per-layer kernels ----------------

// xs = in @ W ; a_srcv[n,h] = xs[n,h,:].a_s[h,:] ; a_dstv likewise
template <int DIN>
__global__ __launch_bounds__(256) void feat_kernel(
    const float* __restrict__ in, const float* __restrict__ W,
    const float* __restrict__ a_s, const float* __restrict__ a_d,
    float* __restrict__ xs, float* __restrict__ a_srcv, float* __restrict__ a_dstv) {
    __shared__ float Wl[DIN * 64];
    __shared__ float asl[64], adl[64];
    int tid = threadIdx.x;
    for (int i = tid; i < DIN * 64; i += 256) Wl[i] = W[i];
    if (tid < 64) { asl[tid] = a_s[tid]; adl[tid] = a_d[tid]; }
    __syncthreads();
    int n = blockIdx.x * 256 + tid;
    if (n >= N_NODES) return;
    float acc[64];
    #pragma unroll
    for (int j = 0; j < 64; ++j) acc[j] = 0.f;
    const float* row = in + (size_t)n * DIN;
    for (int k = 0; k < DIN; ++k) {
        float xk = row[k];
        #pragma unroll
        for (int j = 0; j < 64; ++j) acc[j] += xk * Wl[k * 64 + j];
    }
    float s0 = 0, s1 = 0, d0 = 0, d1 = 0;
    #pragma unroll
    for (int c = 0; c < 32; ++c) {
        s0 += acc[c] * asl[c];           d0 += acc[c] * adl[c];
        s1 += acc[32 + c] * asl[32 + c]; d1 += acc[32 + c] * adl[32 + c];
    }
    a_srcv[n * 2 + 0] = s0; a_srcv[n * 2 + 1] = s1;
    a_dstv[n * 2 + 0] = d0; a_dstv[n * 2 + 1] = d1;
    float4* o = (float4*)(xs + (size_t)n * 64);
    #pragma unroll
    for (int j = 0; j < 16; ++j)
        o[j] = make_float4(acc[4 * j], acc[4 * j + 1], acc[4 * j + 2], acc[4 * j + 3]);
}

// one wave per node: fused logits + online softmax + aggregation, no atomics
__global__ __launch_bounds__(256) void node_agg_kernel(
    const int* __restrict__ rowptr, const int* __restrict__ srcS,
    const float* __restrict__ aeL,     // [N_EP][2] for this layer
    const float* __restrict__ a_srcv, const float* __restrict__ a_dstv,
    const float* __restrict__ xs, const float* __restrict__ b,
    float* __restrict__ out, int relu) {
    int wid = blockIdx.x * 4 + (threadIdx.x >> 6);
    int lane = threadIdx.x & 63;
    if (wid >= N_NODES) return;
    int beg = rowptr[wid], end = rowptr[wid + 1];
    float ad0 = a_dstv[wid * 2], ad1 = a_dstv[wid * 2 + 1];
    int h = lane >> 5;
    float m0 = -INFINITY, m1 = -INFINITY;
    float acc = 0.f, den = 0.f;
    for (int cb = beg; cb < end; cb += 64) {
        int j = cb + lane;
        int s = 0;
        float l0 = -INFINITY, l1 = -INFINITY;
        if (j < end) {
            s = srcS[j];
            float2 ae = ((const float2*)aeL)[j];
            float2 as = ((const float2*)a_srcv)[s];
            l0 = as.x + ad0 + ae.x;
            l1 = as.y + ad1 + ae.y;
            l0 = (l0 > 0.f) ? l0 : 0.2f * l0;
            l1 = (l1 > 0.f) ? l1 : 0.2f * l1;
        }
        // chunk max
        float c0 = l0, c1 = l1;
        #pragma unroll
        for (int o = 32; o; o >>= 1) {
            c0 = fmaxf(c0, __shfl_xor(c0, o));
            c1 = fmaxf(c1, __shfl_xor(c1, o));
        }
        float n0 = fmaxf(m0, c0), n1 = fmaxf(m1, c1);
        float scale = h ? expf(m1 - n1) : expf(m0 - n0);  // exp(-inf)=0 on first chunk; acc,den=0
        acc *= scale; den *= scale;
        m0 = n0; m1 = n1;
        float ex0 = expf(l0 - m0);   // invalid lanes: exp(-inf) = 0
        float ex1 = expf(l1 - m1);
        int cnt = min(end - cb, 64);
        for (int t = 0; t < cnt; ++t) {
            float e0 = __shfl(ex0, t);
            float e1 = __shfl(ex1, t);
            int   sj = __shfl(s, t);
            float ex = h ? e1 : e0;
            den += ex;
            acc += ex * xs[(size_t)sj * 64 + lane];
        }
    }
    float v = acc / (den + 1e-16f) + b[lane];
    if (relu) v = fmaxf(v, 0.f);
    out[(size_t)wid * 64 + lane] = v;
}

// ---------------- tail ----------------

// one block per group, segment mean (batch sorted, no atomics)
__global__ __launch_bounds__(256) void pool_kernel(const float* __restrict__ hfeat,
                                                   const int* __restrict__ gstart,
                                                   float* __restrict__ pooled) {
    __shared__ float sm[4][64];
    int g = blockIdx.x;
    int w = threadIdx.x >> 6, lane = threadIdx.x & 63;
    int beg = gstart[g], end = gstart[g + 1];
    float acc = 0.f;
    for (int n = beg + w; n < end; n += 4)
        acc += hfeat[(size_t)n * 64 + lane];
    sm[w][lane] = acc;
    __syncthreads();
    if (w == 0) {
        float v = sm[0][lane] + sm[1][lane] + sm[2][lane] + sm[3][lane];
        pooled[g * 64 + lane] = v / fmaxf((float)(end - beg), 1.f);
    }
}

__global__ void head_kernel(const float* __restrict__ pooled,
                            const float* __restrict__ Wl, const float* __restrict__ bl,
                            float* __restrict__ out) {
    int t = blockIdx.x * blockDim.x + threadIdx.x;
    if (t >= N_G * N_ACT) return;
    int g = t >> 3, a = t & 7;
    float s = bl[a];
    #pragma unroll
    for (int j = 0; j < 64; ++j) s += pooled[g * 64 + j] * Wl[j * 8 + a];
    out[t] = tanhf(s);
}

extern "C" void kernel_launch(void* const* d_in, const int* in_sizes, int n_in,
                              void* d_out, int out_size, void* d_ws, size_t ws_size,
                              hipStream_t stream) {
    const float* x    = (const float*)d_in[0];
    const int*   ei   = (const int*)d_in[1];
    const float* ea   = (const float*)d_in[2];
    const int*   batch= (const int*)d_in[3];
    const float* W[3]   = {(const float*)d_in[4],  (const float*)d_in[10], (const float*)d_in[16]};
    const float* We[3]  = {(const float*)d_in[5],  (const float*)d_in[11], (const float*)d_in[17]};
    const float* as_[3] = {(const float*)d_in[6],  (const float*)d_in[12], (const float*)d_in[18]};
    const float* ad_[3] = {(const float*)d_in[7],  (const float*)d_in[13], (const float*)d_in[19]};
    const float* ae_[3] = {(const float*)d_in[8],  (const float*)d_in[14], (const float*)d_in[20]};
    const float* b_[3]  = {(const float*)d_in[9],  (const float*)d_in[15], (const float*)d_in[21]};
    const float* Wlin = (const float*)d_in[22];
    const float* bl   = (const float*)d_in[23];
    float* out = (float*)d_out;

    float* ws = (float*)d_ws;
    size_t off = 0;
    float* A      = ws + off; off += (size_t)N_NODES * 64;   // layer io
    float* B      = ws + off; off += (size_t)N_NODES * 64;   // xs
    float* aeL0   = ws + off; off += (size_t)N_EP * 2;
    float* aeL1   = ws + off; off += (size_t)N_EP * 2;
    float* aeL2   = ws + off; off += (size_t)N_EP * 2;
    float* a_srcv = ws + off; off += N_NODES * 2;
    float* a_dstv = ws + off; off += N_NODES * 2;
    float* weff   = ws + off; off += 32;
    float* pooled = ws + off; off += N_G * 64;
    int* srcS   = (int*)(ws + off); off += N_EP;
    int* rowptr = (int*)(ws + off); off += N_NODES + 1;
    int* hist   = (int*)(ws + off); off += N_NODES;
    int* cur    = (int*)(ws + off); off += N_NODES;
    int* gstart = (int*)(ws + off); off += N_G + 1;

    float* aeLs[3] = {aeL0, aeL1, aeL2};

    // ---- once-per-call setup ----
    hipMemsetAsync(hist, 0, N_NODES * sizeof(int), stream);
    hipMemsetAsync(cur, 0, N_NODES * sizeof(int), stream);
    weff_kernel<<<1, 32, 0, stream>>>(We[0], ae_[0], We[1], ae_[1], We[2], ae_[2], weff);
    hist_kernel<<<(N_EDGES + 255) / 256, 256, 0, stream>>>(ei, hist);
    scan_kernel<<<1, 1024, 0, stream>>>(hist, rowptr);
    scatter_kernel<<<(N_EDGES + 255) / 256, 256, 0, stream>>>(ei, ea, weff, rowptr, cur,
                                                              srcS, aeL0, aeL1, aeL2);
    selfloop_kernel<<<(N_NODES + 3) / 4, 256, 0, stream>>>(rowptr, srcS, aeL0, aeL1, aeL2);
    gstart_kernel<<<1, 256, 0, stream>>>(batch, gstart);

    for (int l = 0; l < 3; ++l) {
        if (l == 0)
            feat_kernel<32><<<(N_NODES + 255) / 256, 256, 0, stream>>>(x, W[0], as_[0], ad_[0], B, a_srcv, a_dstv);
        else
            feat_kernel<64><<<(N_NODES + 255) / 256, 256, 0, stream>>>(A, W[l], as_[l], ad_[l], B, a_srcv, a_dstv);
        node_agg_kernel<<<(N_NODES + 3) / 4, 256, 0, stream>>>(rowptr, srcS, aeLs[l],
                                                               a_srcv, a_dstv, B,
                                                               b_[l], A, l < 2 ? 1 : 0);
    }
    pool_kernel<<<N_G, 256, 0, stream>>>(A, gstart, pooled);
    head_kernel<<<(N_G * N_ACT + 255) / 256, 256, 0, stream>>>(pooled, Wlin, bl, out);
}

// Round 4
// 474.923 us; speedup vs baseline: 7.0795x; 1.3150x over previous
//
#include <hip/hip_runtime.h>
#include <math.h>

#define N_NODES 50000
#define N_EDGES 800000
#define N_EP    850000   // E + N self loops
#define E_DIM   5
#define N_G     128
#define N_ACT   8
#define SBLK    512
#define SNB     ((N_NODES + SBLK - 1) / SBLK)   // 98

// ---------------- once-per-call setup kernels ----------------

// weff[l*10 + d*2 + h] = sum_c We_l[d, h*32+c] * ae_l[h, c]
__global__ void weff_kernel(const float* __restrict__ We1, const float* __restrict__ ae1,
                            const float* __restrict__ We2, const float* __restrict__ ae2,
                            const float* __restrict__ We3, const float* __restrict__ ae3,
                            float* __restrict__ weff) {
    int t = threadIdx.x;
    if (t >= 30) return;
    int l = t / 10, r = t % 10, d = r >> 1, h = r & 1;
    const float* We = (l == 0) ? We1 : (l == 1) ? We2 : We3;
    const float* ae = (l == 0) ? ae1 : (l == 1) ? ae2 : ae3;
    float s = 0.f;
    for (int c = 0; c < 32; ++c) s += We[d * 64 + h * 32 + c] * ae[h * 32 + c];
    weff[l * 10 + d * 2 + h] = s;
}

__global__ void hist_kernel(const int* __restrict__ ei, int* __restrict__ hist) {
    int k = blockIdx.x * blockDim.x + threadIdx.x;
    if (k < N_EDGES) atomicAdd(&hist[ei[N_EDGES + k]], 1);
}

__device__ __forceinline__ int wave_incl_scan(int v, int lane) {
    #pragma unroll
    for (int off = 1; off < 64; off <<= 1) {
        int n = __shfl_up(v, off);
        if (lane >= off) v += n;
    }
    return v;
}

// per-block sums of (hist[i]+1)
__global__ __launch_bounds__(SBLK) void scan_bsum_kernel(const int* __restrict__ hist,
                                                         int* __restrict__ bsum) {
    int i = blockIdx.x * SBLK + threadIdx.x;
    int v = (i < N_NODES) ? hist[i] + 1 : 0;
    __shared__ int sm[SBLK / 64];
    int lane = threadIdx.x & 63, w = threadIdx.x >> 6;
    #pragma unroll
    for (int o = 32; o; o >>= 1) v += __shfl_xor(v, o);
    if (lane == 0) sm[w] = v;
    __syncthreads();
    if (threadIdx.x == 0) {
        int s = 0;
        #pragma unroll
        for (int k = 0; k < SBLK / 64; ++k) s += sm[k];
        bsum[blockIdx.x] = s;
    }
}

// exclusive scan of the 98 block sums, in place
__global__ __launch_bounds__(128) void scan_boffs_kernel(int* __restrict__ bsum) {
    int t = threadIdx.x;
    int v = (t < SNB) ? bsum[t] : 0;
    int lane = t & 63, w = t >> 6;
    int inc = wave_incl_scan(v, lane);
    __shared__ int wtot[2];
    if (lane == 63) wtot[w] = inc;
    __syncthreads();
    int base = (w == 1) ? wtot[0] : 0;
    if (t < SNB) bsum[t] = base + inc - v;
}

__global__ __launch_bounds__(SBLK) void scan_rowptr_kernel(const int* __restrict__ hist,
                                                           const int* __restrict__ bsum,
                                                           int* __restrict__ rowptr) {
    int i = blockIdx.x * SBLK + threadIdx.x;
    int v = (i < N_NODES) ? hist[i] + 1 : 0;
    int lane = threadIdx.x & 63, w = threadIdx.x >> 6;
    int inc = wave_incl_scan(v, lane);
    __shared__ int wtot[SBLK / 64];
    if (lane == 63) wtot[w] = inc;
    __syncthreads();
    int woff = 0;
    for (int k = 0; k < w; ++k) woff += wtot[k];
    int excl = bsum[blockIdx.x] + woff + inc - v;
    if (i < N_NODES) rowptr[i] = excl;
    if (i == N_NODES - 1) rowptr[N_NODES] = excl + v;
}

// scatter real edges dst-sorted into packed 32B records:
// rec[pos*8 + {0..5}] = e . weff_{l0,l1,l2} (2 heads each), [6]=src bits, [7]=pad.
// Last slot of each row is reserved for the self loop.
__global__ void scatter_kernel(const int* __restrict__ ei, const float* __restrict__ ea,
                               const float* __restrict__ weff,
                               const int* __restrict__ rowptr, int* __restrict__ cur,
                               float* __restrict__ rec) {
    int k = blockIdx.x * blockDim.x + threadIdx.x;
    if (k >= N_EDGES) return;
    int s = ei[k], d = ei[N_EDGES + k];
    const float* ep = ea + (size_t)k * E_DIM;
    float e[5];
    #pragma unroll
    for (int j = 0; j < 5; ++j) e[j] = ep[j];
    float r[6] = {0.f, 0.f, 0.f, 0.f, 0.f, 0.f};
    #pragma unroll
    for (int j = 0; j < 5; ++j) {
        r[0] += e[j] * weff[j * 2];      r[1] += e[j] * weff[j * 2 + 1];
        r[2] += e[j] * weff[10 + j * 2]; r[3] += e[j] * weff[10 + j * 2 + 1];
        r[4] += e[j] * weff[20 + j * 2]; r[5] += e[j] * weff[20 + j * 2 + 1];
    }
    int pos = rowptr[d] + atomicAdd(&cur[d], 1);
    float4* rp = (float4*)(rec + (size_t)pos * 8);
    rp[0] = make_float4(r[0], r[1], r[2], r[3]);
    rp[1] = make_float4(r[4], r[5], __int_as_float(s), 0.f);
}

// fill self-loop slot of each row with mean of the row's real-edge records
__global__ __launch_bounds__(256) void selfloop_kernel(const int* __restrict__ rowptr,
                                                       float* __restrict__ rec) {
    int wid = blockIdx.x * 4 + (threadIdx.x >> 6);
    int lane = threadIdx.x & 63;
    if (wid >= N_NODES) return;
    int beg = rowptr[wid], endReal = rowptr[wid + 1] - 1;
    float s0 = 0, s1 = 0, s2 = 0, s3 = 0, s4 = 0, s5 = 0;
    for (int j = beg + lane; j < endReal; j += 64) {
        const float4* rp = (const float4*)(rec + (size_t)j * 8);
        float4 a = rp[0], c = rp[1];
        s0 += a.x; s1 += a.y; s2 += a.z; s3 += a.w; s4 += c.x; s5 += c.y;
    }
    #pragma unroll
    for (int o = 32; o; o >>= 1) {
        s0 += __shfl_xor(s0, o); s1 += __shfl_xor(s1, o); s2 += __shfl_xor(s2, o);
        s3 += __shfl_xor(s3, o); s4 += __shfl_xor(s4, o); s5 += __shfl_xor(s5, o);
    }
    if (lane == 0) {
        float inv = 1.f / fmaxf((float)(endReal - beg), 1.f);
        float4* rp = (float4*)(rec + (size_t)endReal * 8);
        rp[0] = make_float4(s0 * inv, s1 * inv, s2 * inv, s3 * inv);
        rp[1] = make_float4(s4 * inv, s5 * inv, __int_as_float(wid), 0.f);
    }
}

// group boundaries in sorted batch
__global__ void gstart_kernel(const int* __restrict__ batch, int* __restrict__ gstart) {
    int g = threadIdx.x;
    if (g > N_G) return;
    int lo = 0, hi = N_NODES;
    while (lo < hi) { int mid = (lo + hi) >> 1; if (batch[mid] < g) lo = mid + 1; else hi = mid; }
    gstart[g] = lo;
}

// ---------------- per-layer kernels ----------------

template <int DIN>
__global__ __launch_bounds__(256) void feat_kernel(
    const float* __restrict__ in, const float* __restrict__ W,
    const float* __restrict__ a_s, const float* __restrict__ a_d,
    float* __restrict__ xs, float* __restrict__ a_srcv, float* __restrict__ a_dstv) {
    __shared__ float Wl[DIN * 64];
    __shared__ float asl[64], adl[64];
    int tid = threadIdx.x;
    for (int i = tid; i < DIN * 64; i += 256) Wl[i] = W[i];
    if (tid < 64) { asl[tid] = a_s[tid]; adl[tid] = a_d[tid]; }
    __syncthreads();
    int n = blockIdx.x * 256 + tid;
    if (n >= N_NODES) return;
    float acc[64];
    #pragma unroll
    for (int j = 0; j < 64; ++j) acc[j] = 0.f;
    const float* row = in + (size_t)n * DIN;
    for (int k = 0; k < DIN; ++k) {
        float xk = row[k];
        #pragma unroll
        for (int j = 0; j < 64; ++j) acc[j] += xk * Wl[k * 64 + j];
    }
    float s0 = 0, s1 = 0, d0 = 0, d1 = 0;
    #pragma unroll
    for (int c = 0; c < 32; ++c) {
        s0 += acc[c] * asl[c];           d0 += acc[c] * adl[c];
        s1 += acc[32 + c] * asl[32 + c]; d1 += acc[32 + c] * adl[32 + c];
    }
    a_srcv[n * 2 + 0] = s0; a_srcv[n * 2 + 1] = s1;
    a_dstv[n * 2 + 0] = d0; a_dstv[n * 2 + 1] = d1;
    float4* o = (float4*)(xs + (size_t)n * 64);
    #pragma unroll
    for (int j = 0; j < 16; ++j)
        o[j] = make_float4(acc[4 * j], acc[4 * j + 1], acc[4 * j + 2], acc[4 * j + 3]);
}

// one wave per node, fused logits + online softmax + aggregation.
// 4 lane-groups of 16 process 4 edges/iter with float4 row gathers.
template <int L>
__global__ __launch_bounds__(256) void node_agg_kernel(
    const int* __restrict__ rowptr, const float* __restrict__ rec,
    const float* __restrict__ a_srcv, const float* __restrict__ a_dstv,
    const float* __restrict__ xs, const float* __restrict__ b,
    float* __restrict__ out, int relu) {
    int wid = blockIdx.x * 4 + (threadIdx.x >> 6);
    int lane = threadIdx.x & 63;
    if (wid >= N_NODES) return;
    int beg = rowptr[wid], end = rowptr[wid + 1];
    float ad0 = a_dstv[wid * 2], ad1 = a_dstv[wid * 2 + 1];
    int g = lane >> 4, fl = lane & 15, h = fl >> 3;
    float m0 = -INFINITY, m1 = -INFINITY;
    float4 acc = make_float4(0.f, 0.f, 0.f, 0.f);
    float den = 0.f;
    for (int cb = beg; cb < end; cb += 64) {
        int j = cb + lane;
        float l0 = -INFINITY, l1 = -INFINITY;
        int s = 0;
        if (j < end) {
            const float4* rp = (const float4*)(rec + (size_t)j * 8);
            float4 r0 = rp[0];
            float4 r1 = rp[1];
            s = __float_as_int(r1.z);
            float aex = (L == 0) ? r0.x : (L == 1) ? r0.z : r1.x;
            float aey = (L == 0) ? r0.y : (L == 1) ? r0.w : r1.y;
            float2 as = ((const float2*)a_srcv)[s];
            l0 = as.x + ad0 + aex;
            l1 = as.y + ad1 + aey;
            l0 = (l0 > 0.f) ? l0 : 0.2f * l0;
            l1 = (l1 > 0.f) ? l1 : 0.2f * l1;
        }
        float c0 = l0, c1 = l1;
        #pragma unroll
        for (int o = 32; o; o >>= 1) {
            c0 = fmaxf(c0, __shfl_xor(c0, o));
            c1 = fmaxf(c1, __shfl_xor(c1, o));
        }
        float n0 = fmaxf(m0, c0), n1 = fmaxf(m1, c1);
        float scale = h ? expf(m1 - n1) : expf(m0 - n0);  // first chunk: exp(-inf)=0
        acc.x *= scale; acc.y *= scale; acc.z *= scale; acc.w *= scale;
        den *= scale;
        m0 = n0; m1 = n1;
        float ex0 = expf(l0 - m0);   // invalid lanes -> 0
        float ex1 = expf(l1 - m1);
        int cnt = min(end - cb, 64);
        for (int t4 = 0; t4 < cnt; t4 += 4) {
            int t = t4 + g;                 // t <= 63 always; lanes >= cnt carry ex=0, s=0
            float e0 = __shfl(ex0, t);
            float e1 = __shfl(ex1, t);
            int sj = __shfl(s, t);
            float exh = h ? e1 : e0;
            float4 xv = *(const float4*)(xs + (size_t)sj * 64 + fl * 4);
            acc.x += exh * xv.x; acc.y += exh * xv.y;
            acc.z += exh * xv.z; acc.w += exh * xv.w;
            den += exh;
        }
    }
    #pragma unroll
    for (int o = 16; o <= 32; o <<= 1) {   // cross-group reduce
        acc.x += __shfl_xor(acc.x, o); acc.y += __shfl_xor(acc.y, o);
        acc.z += __shfl_xor(acc.z, o); acc.w += __shfl_xor(acc.w, o);
        den   += __shfl_xor(den, o);
    }
    if (lane < 16) {
        float inv = 1.f / (den + 1e-16f);
        float4 b4 = ((const float4*)b)[fl];
        float4 v = make_float4(acc.x * inv + b4.x, acc.y * inv + b4.y,
                               acc.z * inv + b4.z, acc.w * inv + b4.w);
        if (relu) {
            v.x = fmaxf(v.x, 0.f); v.y = fmaxf(v.y, 0.f);
            v.z = fmaxf(v.z, 0.f); v.w = fmaxf(v.w, 0.f);
        }
        ((float4*)(out + (size_t)wid * 64))[fl] = v;
    }
}

// ---------------- tail ----------------

__global__ __launch_bounds__(256) void pool_kernel(const float* __restrict__ hfeat,
                                                   const int* __restrict__ gstart,
                                                   float* __restrict__ pooled) {
    __shared__ float sm[4][64];
    int g = blockIdx.x;
    int w = threadIdx.x >> 6, lane = threadIdx.x & 63;
    int beg = gstart[g], end = gstart[g + 1];
    float acc = 0.f;
    for (int n = beg + w; n < end; n += 4)
        acc += hfeat[(size_t)n * 64 + lane];
    sm[w][lane] = acc;
    __syncthreads();
    if (w == 0) {
        float v = sm[0][lane] + sm[1][lane] + sm[2][lane] + sm[3][lane];
        pooled[g * 64 + lane] = v / fmaxf((float)(end - beg), 1.f);
    }
}

__global__ void head_kernel(const float* __restrict__ pooled,
                            const float* __restrict__ Wl, const float* __restrict__ bl,
                            float* __restrict__ out) {
    int t = blockIdx.x * blockDim.x + threadIdx.x;
    if (t >= N_G * N_ACT) return;
    int g = t >> 3, a = t & 7;
    float s = bl[a];
    #pragma unroll
    for (int j = 0; j < 64; ++j) s += pooled[g * 64 + j] * Wl[j * 8 + a];
    out[t] = tanhf(s);
}

extern "C" void kernel_launch(void* const* d_in, const int* in_sizes, int n_in,
                              void* d_out, int out_size, void* d_ws, size_t ws_size,
                              hipStream_t stream) {
    const float* x    = (const float*)d_in[0];
    const int*   ei   = (const int*)d_in[1];
    const float* ea   = (const float*)d_in[2];
    const int*   batch= (const int*)d_in[3];
    const float* W[3]   = {(const float*)d_in[4],  (const float*)d_in[10], (const float*)d_in[16]};
    const float* We[3]  = {(const float*)d_in[5],  (const float*)d_in[11], (const float*)d_in[17]};
    const float* as_[3] = {(const float*)d_in[6],  (const float*)d_in[12], (const float*)d_in[18]};
    const float* ad_[3] = {(const float*)d_in[7],  (const float*)d_in[13], (const float*)d_in[19]};
    const float* ae_[3] = {(const float*)d_in[8],  (const float*)d_in[14], (const float*)d_in[20]};
    const float* b_[3]  = {(const float*)d_in[9],  (const float*)d_in[15], (const float*)d_in[21]};
    const float* Wlin = (const float*)d_in[22];
    const float* bl   = (const float*)d_in[23];
    float* out = (float*)d_out;

    float* ws = (float*)d_ws;
    size_t off = 0;
    float* A      = ws + off; off += (size_t)N_NODES * 64;
    float* B      = ws + off; off += (size_t)N_NODES * 64;
    float* rec    = ws + off; off += (size_t)N_EP * 8;       // packed edge records
    float* a_srcv = ws + off; off += N_NODES * 2;
    float* a_dstv = ws + off; off += N_NODES * 2;
    float* weff   = ws + off; off += 32;
    float* pooled = ws + off; off += N_G * 64;
    int* rowptr = (int*)(ws + off); off += N_NODES + 1;
    int* hist   = (int*)(ws + off); off += N_NODES;
    int* cur    = (int*)(ws + off); off += N_NODES;
    int* gstart = (int*)(ws + off); off += N_G + 1;
    int* bsum   = (int*)(ws + off); off += SNB;

    // ---- once-per-call setup ----
    hipMemsetAsync(hist, 0, N_NODES * sizeof(int), stream);
    hipMemsetAsync(cur, 0, N_NODES * sizeof(int), stream);
    weff_kernel<<<1, 32, 0, stream>>>(We[0], ae_[0], We[1], ae_[1], We[2], ae_[2], weff);
    hist_kernel<<<(N_EDGES + 255) / 256, 256, 0, stream>>>(ei, hist);
    scan_bsum_kernel<<<SNB, SBLK, 0, stream>>>(hist, bsum);
    scan_boffs_kernel<<<1, 128, 0, stream>>>(bsum);
    scan_rowptr_kernel<<<SNB, SBLK, 0, stream>>>(hist, bsum, rowptr);
    scatter_kernel<<<(N_EDGES + 255) / 256, 256, 0, stream>>>(ei, ea, weff, rowptr, cur, rec);
    selfloop_kernel<<<(N_NODES + 3) / 4, 256, 0, stream>>>(rowptr, rec);
    gstart_kernel<<<1, 256, 0, stream>>>(batch, gstart);

    const int NB = (N_NODES + 3) / 4;
    for (int l = 0; l < 3; ++l) {
        if (l == 0)
            feat_kernel<32><<<(N_NODES + 255) / 256, 256, 0, stream>>>(x, W[0], as_[0], ad_[0], B, a_srcv, a_dstv);
        else
            feat_kernel<64><<<(N_NODES + 255) / 256, 256, 0, stream>>>(A, W[l], as_[l], ad_[l], B, a_srcv, a_dstv);
        if (l == 0)
            node_agg_kernel<0><<<NB, 256, 0, stream>>>(rowptr, rec, a_srcv, a_dstv, B, b_[0], A, 1);
        else if (l == 1)
            node_agg_kernel<1><<<NB, 256, 0, stream>>>(rowptr, rec, a_srcv, a_dstv, B, b_[1], A, 1);
        else
            node_agg_kernel<2><<<NB, 256, 0, stream>>>(rowptr, rec, a_srcv, a_dstv, B, b_[2], A, 0);
    }
    pool_kernel<<<N_G, 256, 0, stream>>>(A, gstart, pooled);
    head_kernel<<<(N_G * N_ACT + 255) / 256, 256, 0, stream>>>(pooled, Wlin, bl, out);
}

// Round 6
// 389.995 us; speedup vs baseline: 8.6212x; 1.2178x over previous
//
#include <hip/hip_runtime.h>
#include <math.h>

#define N_NODES 50000
#define N_EDGES 800000
#define E_DIM   5
#define N_G     128
#define N_ACT   8
#define SBLK    512
#define SNB     ((N_NODES + SBLK - 1) / SBLK)   // 98

// ---------------- once-per-call setup ----------------

// block 0: weff (t in [160,190)) + gstart (t in [0,129)); blocks 1..: hist
__global__ __launch_bounds__(256) void setup_kernel(
    const int* __restrict__ ei, const int* __restrict__ batch,
    const float* __restrict__ We1, const float* __restrict__ ae1,
    const float* __restrict__ We2, const float* __restrict__ ae2,
    const float* __restrict__ We3, const float* __restrict__ ae3,
    float* __restrict__ weff, int* __restrict__ gstart, int* __restrict__ hist) {
    int bid = blockIdx.x, tid = threadIdx.x;
    if (bid == 0) {
        if (tid <= N_G) {  // group boundaries in sorted batch
            int g = tid, lo = 0, hi = N_NODES;
            while (lo < hi) { int mid = (lo + hi) >> 1; if (batch[mid] < g) lo = mid + 1; else hi = mid; }
            gstart[g] = lo;
        }
        int t = tid - 160;
        if (t >= 0 && t < 30) {  // weff[l*10 + d*2 + h] = sum_c We_l[d, h*32+c]*ae_l[h,c]
            int l = t / 10, r = t % 10, d = r >> 1, h = r & 1;
            const float* We = (l == 0) ? We1 : (l == 1) ? We2 : We3;
            const float* ae = (l == 0) ? ae1 : (l == 1) ? ae2 : ae3;
            float s = 0.f;
            for (int c = 0; c < 32; ++c) s += We[d * 64 + h * 32 + c] * ae[h * 32 + c];
            weff[l * 10 + d * 2 + h] = s;
        }
        return;
    }
    int k = (bid - 1) * 256 + tid;
    if (k < N_EDGES) atomicAdd(&hist[ei[N_EDGES + k]], 1);
}

__device__ __forceinline__ int wave_incl_scan(int v, int lane) {
    #pragma unroll
    for (int off = 1; off < 64; off <<= 1) {
        int n = __shfl_up(v, off);
        if (lane >= off) v += n;
    }
    return v;
}

__global__ __launch_bounds__(SBLK) void scan_bsum_kernel(const int* __restrict__ hist,
                                                         int* __restrict__ bsum) {
    int i = blockIdx.x * SBLK + threadIdx.x;
    int v = (i < N_NODES) ? hist[i] : 0;
    __shared__ int sm[SBLK / 64];
    int lane = threadIdx.x & 63, w = threadIdx.x >> 6;
    #pragma unroll
    for (int o = 32; o; o >>= 1) v += __shfl_xor(v, o);
    if (lane == 0) sm[w] = v;
    __syncthreads();
    if (threadIdx.x == 0) {
        int s = 0;
        #pragma unroll
        for (int k = 0; k < SBLK / 64; ++k) s += sm[k];
        bsum[blockIdx.x] = s;
    }
}

__global__ __launch_bounds__(128) void scan_boffs_kernel(int* __restrict__ bsum) {
    int t = threadIdx.x;
    int v = (t < SNB) ? bsum[t] : 0;
    int lane = t & 63, w = t >> 6;
    int inc = wave_incl_scan(v, lane);
    __shared__ int wtot[2];
    if (lane == 63) wtot[w] = inc;
    __syncthreads();
    int base = (w == 1) ? wtot[0] : 0;
    if (t < SNB) bsum[t] = base + inc - v;
}

__global__ __launch_bounds__(SBLK) void scan_rowptr_kernel(const int* __restrict__ hist,
                                                           const int* __restrict__ bsum,
                                                           int* __restrict__ rowptr) {
    int i = blockIdx.x * SBLK + threadIdx.x;
    int v = (i < N_NODES) ? hist[i] : 0;
    int lane = threadIdx.x & 63, w = threadIdx.x >> 6;
    int inc = wave_incl_scan(v, lane);
    __shared__ int wtot[SBLK / 64];
    if (lane == 63) wtot[w] = inc;
    __syncthreads();
    int woff = 0;
    for (int k = 0; k < w; ++k) woff += wtot[k];
    int excl = bsum[blockIdx.x] + woff + inc - v;
    if (i < N_NODES) rowptr[i] = excl;
    if (i == N_NODES - 1) rowptr[N_NODES] = excl + v;
}

// scatter real edges dst-sorted into packed 32B records:
// rec[pos*8 + {0..5}] = e . weff_{l0,l1,l2}, [6]=src bits, [7]=pad
__global__ void scatter_kernel(const int* __restrict__ ei, const float* __restrict__ ea,
                               const float* __restrict__ weff,
                               const int* __restrict__ rowptr, int* __restrict__ cur,
                               float* __restrict__ rec) {
    int k = blockIdx.x * blockDim.x + threadIdx.x;
    if (k >= N_EDGES) return;
    int s = ei[k], d = ei[N_EDGES + k];
    const float* ep = ea + (size_t)k * E_DIM;
    float e[5];
    #pragma unroll
    for (int j = 0; j < 5; ++j) e[j] = ep[j];
    float r[6] = {0.f, 0.f, 0.f, 0.f, 0.f, 0.f};
    #pragma unroll
    for (int j = 0; j < 5; ++j) {
        r[0] += e[j] * weff[j * 2];      r[1] += e[j] * weff[j * 2 + 1];
        r[2] += e[j] * weff[10 + j * 2]; r[3] += e[j] * weff[10 + j * 2 + 1];
        r[4] += e[j] * weff[20 + j * 2]; r[5] += e[j] * weff[20 + j * 2 + 1];
    }
    int pos = rowptr[d] + atomicAdd(&cur[d], 1);
    float4* rp = (float4*)(rec + (size_t)pos * 8);
    rp[0] = make_float4(r[0], r[1], r[2], r[3]);
    rp[1] = make_float4(r[4], r[5], __int_as_float(s), 0.f);
}

// ---------------- per-layer kernels ----------------

// 4 threads per node (16-col strips); W in LDS read as float4 (2-way alias = free).
template <int DIN>
__global__ __launch_bounds__(256) void feat_kernel(
    const float* __restrict__ in, const float* __restrict__ W,
    const float* __restrict__ a_s, const float* __restrict__ a_d,
    float* __restrict__ xs, float* __restrict__ a_srcv, float* __restrict__ a_dstv) {
    __shared__ float Wl[DIN * 64];
    __shared__ float asl[64], adl[64];
    int tid = threadIdx.x;
    {
        const float4* Wg = (const float4*)W;
        float4* Wl4 = (float4*)Wl;
        #pragma unroll
        for (int i = tid; i < DIN * 16; i += 256) Wl4[i] = Wg[i];
        if (tid < 64) { asl[tid] = a_s[tid]; adl[tid] = a_d[tid]; }
    }
    __syncthreads();
    int n = blockIdx.x * 64 + (tid >> 2);
    int strip = tid & 3;
    if (n >= N_NODES) return;
    // input row into registers (all loads in flight at once)
    float4 xr[DIN / 4];
    const float4* row4 = (const float4*)(in + (size_t)n * DIN);
    #pragma unroll
    for (int k4 = 0; k4 < DIN / 4; ++k4) xr[k4] = row4[k4];
    float4 acc[4];
    #pragma unroll
    for (int j = 0; j < 4; ++j) acc[j] = make_float4(0.f, 0.f, 0.f, 0.f);
    const float4* W4 = (const float4*)Wl;
    #pragma unroll
    for (int k4 = 0; k4 < DIN / 4; ++k4) {
        float xk[4] = {xr[k4].x, xr[k4].y, xr[k4].z, xr[k4].w};
        #pragma unroll
        for (int kk = 0; kk < 4; ++kk) {
            int k = k4 * 4 + kk;
            #pragma unroll
            for (int j = 0; j < 4; ++j) {
                float4 w = W4[k * 16 + strip * 4 + j];
                acc[j].x += xk[kk] * w.x; acc[j].y += xk[kk] * w.y;
                acc[j].z += xk[kk] * w.z; acc[j].w += xk[kk] * w.w;
            }
        }
    }
    // partial attention dots over this strip, reduce across strip pairs
    float ps = 0.f, pd = 0.f;
    #pragma unroll
    for (int j = 0; j < 4; ++j) {
        int c = strip * 16 + j * 4;
        ps += acc[j].x * asl[c] + acc[j].y * asl[c + 1] + acc[j].z * asl[c + 2] + acc[j].w * asl[c + 3];
        pd += acc[j].x * adl[c] + acc[j].y * adl[c + 1] + acc[j].z * adl[c + 2] + acc[j].w * adl[c + 3];
    }
    ps += __shfl_xor(ps, 1);
    pd += __shfl_xor(pd, 1);
    if ((strip & 1) == 0) {
        int h = strip >> 1;
        a_srcv[n * 2 + h] = ps;
        a_dstv[n * 2 + h] = pd;
    }
    float4* o = (float4*)(xs + (size_t)n * 64 + strip * 16);
    #pragma unroll
    for (int j = 0; j < 4; ++j) o[j] = acc[j];
}

// one wave per node: fused logits + online softmax + aggregation + self-loop.
// 4 lane-groups of 16; edge loop unrolled x2 (two gathers in flight).
template <int L>
__global__ __launch_bounds__(256) void node_agg_kernel(
    const int* __restrict__ rowptr, const float* __restrict__ rec,
    const float* __restrict__ a_srcv, const float* __restrict__ a_dstv,
    const float* __restrict__ xs, const float* __restrict__ b,
    float* __restrict__ out, int relu) {
    int wid = blockIdx.x * 4 + (threadIdx.x >> 6);
    int lane = threadIdx.x & 63;
    if (wid >= N_NODES) return;
    int beg = rowptr[wid], end = rowptr[wid + 1];
    float2 ad2 = ((const float2*)a_dstv)[wid];
    int g = lane >> 4, fl = lane & 15, h = fl >> 3;
    float m0 = -INFINITY, m1 = -INFINITY;
    float4 accA = make_float4(0.f, 0.f, 0.f, 0.f);
    float4 accB = make_float4(0.f, 0.f, 0.f, 0.f);
    float denA = 0.f, denB = 0.f;
    float aes0 = 0.f, aes1 = 0.f;   // sum of edge-attr logit terms (for self-loop mean)
    for (int cb = beg; cb < end; cb += 64) {
        int j = cb + lane;
        float l0 = -INFINITY, l1 = -INFINITY;
        int s = 0;
        if (j < end) {
            const float4* rp = (const float4*)(rec + (size_t)j * 8);
            float4 r0 = rp[0];
            float4 r1 = rp[1];
            s = __float_as_int(r1.z);
            float aex = (L == 0) ? r0.x : (L == 1) ? r0.z : r1.x;
            float aey = (L == 0) ? r0.y : (L == 1) ? r0.w : r1.y;
            aes0 += aex; aes1 += aey;
            float2 as2 = ((const float2*)a_srcv)[s];
            l0 = as2.x + ad2.x + aex;
            l1 = as2.y + ad2.y + aey;
            l0 = (l0 > 0.f) ? l0 : 0.2f * l0;
            l1 = (l1 > 0.f) ? l1 : 0.2f * l1;
        }
        float c0 = l0, c1 = l1;
        #pragma unroll
        for (int o = 32; o; o >>= 1) {
            c0 = fmaxf(c0, __shfl_xor(c0, o));
            c1 = fmaxf(c1, __shfl_xor(c1, o));
        }
        float n0 = fmaxf(m0, c0), n1 = fmaxf(m1, c1);
        float scale = h ? expf(m1 - n1) : expf(m0 - n0);  // first chunk: exp(-inf)=0
        accA.x *= scale; accA.y *= scale; accA.z *= scale; accA.w *= scale;
        accB.x *= scale; accB.y *= scale; accB.z *= scale; accB.w *= scale;
        denA *= scale; denB *= scale;
        m0 = n0; m1 = n1;
        float ex0 = expf(l0 - m0);   // invalid lanes -> 0
        float ex1 = expf(l1 - m1);
        int cnt = min(end - cb, 64);
        for (int t8 = 0; t8 < cnt; t8 += 8) {
            int tA = t8 + g;              // <= 59
            int tB = tA + 4;              // <= 63; ex=0 beyond cnt
            float e0 = __shfl(ex0, tA), e1 = __shfl(ex1, tA);
            int sA = __shfl(s, tA);
            float f0 = __shfl(ex0, tB), f1 = __shfl(ex1, tB);
            int sB = __shfl(s, tB);
            float eA = h ? e1 : e0;
            float eB = h ? f1 : f0;
            float4 xv = *(const float4*)(xs + (size_t)sA * 64 + fl * 4);
            float4 yv = *(const float4*)(xs + (size_t)sB * 64 + fl * 4);
            accA.x += eA * xv.x; accA.y += eA * xv.y; accA.z += eA * xv.z; accA.w += eA * xv.w;
            denA += eA;
            accB.x += eB * yv.x; accB.y += eB * yv.y; accB.z += eB * yv.z; accB.w += eB * yv.w;
            denB += eB;
        }
    }
    float4 acc = make_float4(accA.x + accB.x, accA.y + accB.y,
                             accA.z + accB.z, accA.w + accB.w);
    float den = denA + denB;
    #pragma unroll
    for (int o = 16; o <= 32; o <<= 1) {   // cross-group reduce
        acc.x += __shfl_xor(acc.x, o); acc.y += __shfl_xor(acc.y, o);
        acc.z += __shfl_xor(acc.z, o); acc.w += __shfl_xor(acc.w, o);
        den   += __shfl_xor(den, o);
    }
    #pragma unroll
    for (int o = 1; o < 64; o <<= 1) {     // full reduce of ae sums
        aes0 += __shfl_xor(aes0, o);
        aes1 += __shfl_xor(aes1, o);
    }
    if (lane < 16) {
        int ne = end - beg;
        float aeS = (h ? aes1 : aes0) / fmaxf((float)ne, 1.f);
        float2 as2 = ((const float2*)a_srcv)[wid];
        float ls = (h ? as2.y + ad2.y : as2.x + ad2.x) + aeS;
        ls = (ls > 0.f) ? ls : 0.2f * ls;
        float mh = h ? m1 : m0;
        float nm = fmaxf(mh, ls);
        float sc = expf(mh - nm);          // ne==0: exp(-inf)=0
        float exS = expf(ls - nm);
        den = den * sc + exS;
        float4 xv = *(const float4*)(xs + (size_t)wid * 64 + fl * 4);
        float inv = 1.f / (den + 1e-16f);
        float4 b4 = ((const float4*)b)[fl];
        float4 v;
        v.x = (acc.x * sc + exS * xv.x) * inv + b4.x;
        v.y = (acc.y * sc + exS * xv.y) * inv + b4.y;
        v.z = (acc.z * sc + exS * xv.z) * inv + b4.z;
        v.w = (acc.w * sc + exS * xv.w) * inv + b4.w;
        if (relu) {
            v.x = fmaxf(v.x, 0.f); v.y = fmaxf(v.y, 0.f);
            v.z = fmaxf(v.z, 0.f); v.w = fmaxf(v.w, 0.f);
        }
        ((float4*)(out + (size_t)wid * 64))[fl] = v;
    }
}

// ---------------- tail ----------------

__global__ __launch_bounds__(256) void pool_kernel(const float* __restrict__ hfeat,
                                                   const int* __restrict__ gstart,
                                                   float* __restrict__ pooled) {
    __shared__ float sm[4][64];
    int g = blockIdx.x;
    int w = threadIdx.x >> 6, lane = threadIdx.x & 63;
    int beg = gstart[g], end = gstart[g + 1];
    float acc = 0.f;
    for (int n = beg + w; n < end; n += 4)
        acc += hfeat[(size_t)n * 64 + lane];
    sm[w][lane] = acc;
    __syncthreads();
    if (w == 0) {
        float v = sm[0][lane] + sm[1][lane] + sm[2][lane] + sm[3][lane];
        pooled[g * 64 + lane] = v / fmaxf((float)(end - beg), 1.f);
    }
}

__global__ void head_kernel(const float* __restrict__ pooled,
                            const float* __restrict__ Wl, const float* __restrict__ bl,
                            float* __restrict__ out) {
    int t = blockIdx.x * blockDim.x + threadIdx.x;
    if (t >= N_G * N_ACT) return;
    int g = t >> 3, a = t & 7;
    float s = bl[a];
    #pragma unroll
    for (int j = 0; j < 64; ++j) s += pooled[g * 64 + j] * Wl[j * 8 + a];
    out[t] = tanhf(s);
}

extern "C" void kernel_launch(void* const* d_in, const int* in_sizes, int n_in,
                              void* d_out, int out_size, void* d_ws, size_t ws_size,
                              hipStream_t stream) {
    const float* x    = (const float*)d_in[0];
    const int*   ei   = (const int*)d_in[1];
    const float* ea   = (const float*)d_in[2];
    const int*   batch= (const int*)d_in[3];
    const float* W[3]   = {(const float*)d_in[4],  (const float*)d_in[10], (const float*)d_in[16]};
    const float* We[3]  = {(const float*)d_in[5],  (const float*)d_in[11], (const float*)d_in[17]};
    const float* as_[3] = {(const float*)d_in[6],  (const float*)d_in[12], (const float*)d_in[18]};
    const float* ad_[3] = {(const float*)d_in[7],  (const float*)d_in[13], (const float*)d_in[19]};
    const float* ae_[3] = {(const float*)d_in[8],  (const float*)d_in[14], (const float*)d_in[20]};
    const float* b_[3]  = {(const float*)d_in[9],  (const float*)d_in[15], (const float*)d_in[21]};
    const float* Wlin = (const float*)d_in[22];
    const float* bl   = (const float*)d_in[23];
    float* out = (float*)d_out;

    float* ws = (float*)d_ws;
    size_t off = 0;
    float* A      = ws + off; off += (size_t)N_NODES * 64;
    float* B      = ws + off; off += (size_t)N_NODES * 64;
    float* rec    = ws + off; off += (size_t)N_EDGES * 8;    // packed edge records
    float* a_srcv = ws + off; off += N_NODES * 2;
    float* a_dstv = ws + off; off += N_NODES * 2;
    float* weff   = ws + off; off += 32;
    float* pooled = ws + off; off += N_G * 64;
    int* rowptr = (int*)(ws + off); off += N_NODES + 1;
    int* hist   = (int*)(ws + off); off += N_NODES;          // hist+cur contiguous
    int* cur    = (int*)(ws + off); off += N_NODES;
    int* gstart = (int*)(ws + off); off += N_G + 1;
    int* bsum   = (int*)(ws + off); off += SNB;

    // ---- once-per-call setup ----
    hipMemsetAsync(hist, 0, 2 * N_NODES * sizeof(int), stream);   // hist + cur
    setup_kernel<<<1 + (N_EDGES + 255) / 256, 256, 0, stream>>>(
        ei, batch, We[0], ae_[0], We[1], ae_[1], We[2], ae_[2], weff, gstart, hist);
    scan_bsum_kernel<<<SNB, SBLK, 0, stream>>>(hist, bsum);
    scan_boffs_kernel<<<1, 128, 0, stream>>>(bsum);
    scan_rowptr_kernel<<<SNB, SBLK, 0, stream>>>(hist, bsum, rowptr);
    scatter_kernel<<<(N_EDGES + 255) / 256, 256, 0, stream>>>(ei, ea, weff, rowptr, cur, rec);

    const int NB = (N_NODES + 3) / 4;
    const int FB = (N_NODES + 63) / 64;
    for (int l = 0; l < 3; ++l) {
        if (l == 0)
            feat_kernel<32><<<FB, 256, 0, stream>>>(x, W[0], as_[0], ad_[0], B, a_srcv, a_dstv);
        else
            feat_kernel<64><<<FB, 256, 0, stream>>>(A, W[l], as_[l], ad_[l], B, a_srcv, a_dstv);
        if (l == 0)
            node_agg_kernel<0><<<NB, 256, 0, stream>>>(rowptr, rec, a_srcv, a_dstv, B, b_[0], A, 1);
        else if (l == 1)
            node_agg_kernel<1><<<NB, 256, 0, stream>>>(rowptr, rec, a_srcv, a_dstv, B, b_[1], A, 1);
        else
            node_agg_kernel<2><<<NB, 256, 0, stream>>>(rowptr, rec, a_srcv, a_dstv, B, b_[2], A, 0);
    }
    pool_kernel<<<N_G, 256, 0, stream>>>(A, gstart, pooled);
    head_kernel<<<(N_G * N_ACT + 255) / 256, 256, 0, stream>>>(pooled, Wlin, bl, out);
}